// Round 6
// baseline (3816.904 us; speedup 1.0000x reference)
//
#include <hip/hip_runtime.h>

#define BB 16
#define NN 4096
#define DFEAT 20
#define SS 1024
#define KK 32
#define MM (BB*SS*KK)   // 524288

// ---- workspace layout (bytes), total ~73.6 MB ----
#define WS_STATS   0ull          // 8192   (1024 doubles: 3 layers x up to 256ch x {s1,s2})
#define WS_PARAMS  8192ull       // 4096   (floats: layer L at +L*256 floats: {mu,inv} per ch)
#define WS_FPSIDX  12288ull      // 65536
#define WS_CENT    81920ull      // 1572864  ([B*S][24] gathered combined rows)
#define WS_KNN     1654784ull    // 2097152  ([B*S][32] int)
#define WS_COMB    3751936ull    // 6291456  ([B*N][24] fp32, ch23 = 0 pad)
#define WS_YB      10043392ull   // 67108864 (bf16 [64][M]; y1 then overwritten in-place by y2)
#define WS_NEED    77152256ull

typedef float v2f __attribute__((ext_vector_type(2)));

static __device__ __forceinline__ unsigned short f2bf(float f){
    unsigned u = __float_as_uint(f);
    unsigned r = (u + 0x7FFFu + ((u >> 16) & 1u)) >> 16;
    return (unsigned short)r;
}
static __device__ __forceinline__ float bf2f(unsigned short v){
    return __uint_as_float((unsigned)v << 16);
}
// pin a v2f pair into an (even-aligned) VGPR pair: empty asm "redefines" it so
// the compiler cannot rematerialize/spill the FPS point set
static __device__ __forceinline__ void pinv2(v2f& x){
    asm volatile("" : "+v"(x));
}

static __device__ __forceinline__ unsigned long long max64(unsigned long long a, unsigned long long b){
    return a > b ? a : b;
}
// 32-bit DPP-shifted copy; bound_ctrl=1 -> invalid source lanes read 0,
// identity for unsigned max (our operands are > 0 where it matters).
template<int CTRL>
static __device__ __forceinline__ unsigned dpp32_or0(unsigned x){
    return (unsigned)__builtin_amdgcn_update_dpp(0, (int)x, CTRL, 0xf, 0xf, true);
}
static __device__ __forceinline__ unsigned umax32(unsigned a, unsigned b){
    return a > b ? a : b;
}
// wave-wide max chain; full-wave result valid in lane 63
static __device__ __forceinline__ unsigned wave_max_u32(unsigned x){
    x = umax32(x, dpp32_or0<0x111>(x));   // row_shr:1
    x = umax32(x, dpp32_or0<0x112>(x));   // row_shr:2
    x = umax32(x, dpp32_or0<0x114>(x));   // row_shr:4
    x = umax32(x, dpp32_or0<0x118>(x));   // row_shr:8
    x = umax32(x, dpp32_or0<0x142>(x));   // row_bcast:15
    x = umax32(x, dpp32_or0<0x143>(x));   // row_bcast:31
    return x;
}

// ---------------------------------------------------------------------------
// 0) zero the stats area (1024 doubles)
// ---------------------------------------------------------------------------
__global__ void k_zstats(double* __restrict__ stats){
    int t = threadIdx.x;
#pragma unroll
    for (int i = 0; i < 4; ++i) stats[i*256 + t] = 0.0;
}

// fallback when ws is too small: zero d_out so the harness fails cleanly
__global__ void k_fail(float* __restrict__ out, int n){
    int i = blockIdx.x * 256 + threadIdx.x;
    if (i < n) out[i] = 0.f;
}

// ---------------------------------------------------------------------------
// 1) build combined [B][N][24] (ch23 = 0 pad)
// ---------------------------------------------------------------------------
__global__ __launch_bounds__(256) void k_build(const float* __restrict__ xyz,
                                               const float* __restrict__ feat,
                                               float* __restrict__ comb)
{
    int idx = blockIdx.x * 256 + threadIdx.x;   // over B*N = 65536
    int b = idx >> 12, j = idx & 4095;
    float c[24];
    c[0] = xyz[((size_t)b*3 + 0)*NN + j];
    c[1] = xyz[((size_t)b*3 + 1)*NN + j];
    c[2] = xyz[((size_t)b*3 + 2)*NN + j];
    const float* f = feat + ((size_t)b*NN + j)*DFEAT;
#pragma unroll
    for (int d = 0; d < 20; ++d) c[3+d] = f[d];
    c[23] = 0.f;
    float* out = comb + (size_t)idx * 24;
#pragma unroll
    for (int q = 0; q < 6; ++q)
        ((float4*)out)[q] = make_float4(c[4*q], c[4*q+1], c[4*q+2], c[4*q+3]);
}

// ---------------------------------------------------------------------------
// 2) FPS v9: kill the register-file tax. R2->R5 established: issue count
//    halved (R3) with no wall change; VGPR_Count pinned at 116-128 while
//    ~240 floats are live -> ~190 AGPR/scratch round-trips per wave per
//    iteration was the dominant constant cost (R5's 4.8MB scratch WRITE_SIZE
//    made it visible). v9: 256 threads x 16 points/thread at
//    __launch_bounds__(256,1) -> 1 wave/SIMD -> full 512-VGPR budget;
//    ~440 live regs fit with NO AGPR/scratch traffic.
//    Selection bit-identical: packed per-point distance chains in v4 order
//    (R3/R5-validated), two-chain 32-bit DPP reduce + LDS fpsidx buffer
//    (v8-validated logic), R1/R2-style wkey LDS + register tree stage-2,
//    winner-register stash. Only the thread->point mapping changes
//    (idx = t + 256p; same global key & tie-break).
// ---------------------------------------------------------------------------
__global__ __launch_bounds__(256, 1) void k_fps(const float* __restrict__ comb,
                                                int* __restrict__ fpsidx)
{
    int b = blockIdx.x, t = threadIdx.x;
    const float* C = comb + (size_t)b * NN * 24;
    // 16 points/thread as 8 v2f pairs: point p -> pair p>>1 half p&1,
    // global index t + 256*p
    v2f pt2[8][24];
    v2f dist2[8];
#pragma unroll
    for (int p = 0; p < 16; ++p){
        const float4* r = (const float4*)(C + (size_t)(t + 256*p) * 24);
#pragma unroll
        for (int q = 0; q < 6; ++q){
            float4 v = r[q];
            pt2[p>>1][4*q+0][p&1] = v.x;
            pt2[p>>1][4*q+1][p&1] = v.y;
            pt2[p>>1][4*q+2][p&1] = v.z;
            pt2[p>>1][4*q+3][p&1] = v.w;
        }
    }
#pragma unroll
    for (int k = 0; k < 8; ++k){
        dist2[k] = (v2f){1e10f, 1e10f};
#pragma unroll
        for (int q = 0; q < 23; ++q) pinv2(pt2[k][q]);   // ch23 unused -> dies
    }

    __shared__ __align__(16) unsigned long long wkey[2][4];
    __shared__ __align__(16) float wpt[2][4][24];
    __shared__ int fps_lds[SS];
    int lane = t & 63, w = t >> 6;           // 4 waves
    unsigned nt = 0xFFFFFFFFu - (unsigned)t;
    int far = 0;

    float cc[24];
    {
        const float4* crow = (const float4*)C;   // initial centroid: row 0
#pragma unroll
        for (int q = 0; q < 6; ++q){
            float4 cv = crow[q];
            cc[4*q] = cv.x; cc[4*q+1] = cv.y; cc[4*q+2] = cv.z; cc[4*q+3] = cv.w;
        }
    }

    for (int s = 0; s < SS; ++s){
        if (t == 0) fps_lds[s] = far;          // LDS only; flushed post-loop
        // ---- distance update: per-point chain EXACTLY v4's order, executed
        //      as 8 packed float2 chains (each half = one point's scalar
        //      sequence; VOP3P fp32 is IEEE-identical to scalar fp32).
        v2f acc2[8];
#pragma unroll
        for (int k = 0; k < 8; ++k){
            v2f d0 = pt2[k][0] - cc[0];
            acc2[k] = d0 * d0;
        }
#pragma unroll
        for (int q = 1; q < 23; ++q){
            float cq = cc[q];
#pragma unroll
            for (int k = 0; k < 8; ++k){
                v2f dd = pt2[k][q] - cq;
                acc2[k] = __builtin_elementwise_fma(dd, dd, acc2[k]);
            }
        }
        // packed min-update + packed max tree (bit-identical per element;
        // float max == bits max for non-negative values, any tree shape)
#pragma unroll
        for (int k = 0; k < 8; ++k)
            dist2[k] = __builtin_elementwise_min(dist2[k], acc2[k]);
        v2f m0 = __builtin_elementwise_max(dist2[0], dist2[1]);
        v2f m1 = __builtin_elementwise_max(dist2[2], dist2[3]);
        v2f m2 = __builtin_elementwise_max(dist2[4], dist2[5]);
        v2f m3 = __builtin_elementwise_max(dist2[6], dist2[7]);
        v2f n0 = __builtin_elementwise_max(m0, m1);
        v2f n1 = __builtin_elementwise_max(m2, m3);
        v2f mt = __builtin_elementwise_max(n0, n1);
        float mf = fmaxf(mt[0], mt[1]);
        unsigned maxbits = __float_as_uint(mf);    // >=0 -> bits monotone
        // smallest p whose dist-bits equal the max -> min global idx among ties
        int pstar = 0;
#pragma unroll
        for (int p = 15; p >= 0; --p)
            if (__float_as_uint(dist2[p>>1][p&1]) == maxbits) pstar = p;

        // ---- stage-1a: wave max of dist bits (32-bit DPP chain) ----
        unsigned M = __builtin_amdgcn_readlane((int)wave_max_u32(maxbits), 63);
        // ---- stage-1b: among tied lanes, wave max of complemented index
        //      (== min index; 0-fill / non-tied lanes can never win) ----
        unsigned cidx = (maxbits == M) ? (nt - ((unsigned)pstar << 8)) : 0u;
        unsigned widxc = __builtin_amdgcn_readlane((int)wave_max_u32(cidx), 63);
        unsigned widx  = 0xFFFFFFFFu - widxc;      // wave winner global index

        int par = s & 1;
        if (lane == 63)
            wkey[par][w] = ((unsigned long long)M << 32) | (unsigned long long)widxc;
        // wave-winner thread stashes its point row (registers -> LDS, bit-exact)
        if (t == (int)(widx & 255u)){
            int pw = (int)(widx >> 8);
            float* dst = wpt[par][w];
            switch (pw){
#define PE(P,q) pt2[(P)>>1][q][(P)&1]
#define STASH(P) case P: \
                ((float4*)dst)[0] = make_float4(PE(P,0),PE(P,1),PE(P,2),PE(P,3)); \
                ((float4*)dst)[1] = make_float4(PE(P,4),PE(P,5),PE(P,6),PE(P,7)); \
                ((float4*)dst)[2] = make_float4(PE(P,8),PE(P,9),PE(P,10),PE(P,11)); \
                ((float4*)dst)[3] = make_float4(PE(P,12),PE(P,13),PE(P,14),PE(P,15)); \
                ((float4*)dst)[4] = make_float4(PE(P,16),PE(P,17),PE(P,18),PE(P,19)); \
                ((float4*)dst)[5] = make_float4(PE(P,20),PE(P,21),PE(P,22),0.f); \
                break;
            STASH(0)  STASH(1)  STASH(2)  STASH(3)
            STASH(4)  STASH(5)  STASH(6)  STASH(7)
            STASH(8)  STASH(9)  STASH(10) STASH(11)
            STASH(12) STASH(13) STASH(14) STASH(15)
#undef STASH
#undef PE
            }
        }
        __syncthreads();
        // ---- stage-2: broadcast-read the 4 wave keys, register tree max ----
        const ulonglong2* kp = (const ulonglong2*)wkey[par];
        ulonglong2 q0 = kp[0], q1 = kp[1];
        unsigned long long k2 = max64(max64(q0.x, q0.y), max64(q1.x, q1.y));
        far = (int)(0xFFFFFFFFu - (unsigned)(k2 & 0xFFFFFFFFull));
        // next centroid from the winner's stashed registers (LDS broadcast)
        int wg = (far & 255) >> 6;
        const float4* crow = (const float4*)wpt[par][wg];
#pragma unroll
        for (int q = 0; q < 6; ++q){
            float4 cv = crow[q];
            cc[4*q] = cv.x; cc[4*q+1] = cv.y; cc[4*q+2] = cv.z; cc[4*q+3] = cv.w;
        }
    }
    // flush fpsidx (coalesced, once)
    __syncthreads();
#pragma unroll
    for (int i = 0; i < 4; ++i)
        fpsidx[b*SS + i*256 + t] = fps_lds[i*256 + t];
}

// ---------------------------------------------------------------------------
// 3) gather centroids + outputs 0 and 2 (exact gathers)
// ---------------------------------------------------------------------------
__global__ __launch_bounds__(256) void k_gather(const float* __restrict__ comb,
                                                const int* __restrict__ fpsidx,
                                                float* __restrict__ cent,
                                                float* __restrict__ out0,
                                                float* __restrict__ out2)
{
    int idx = blockIdx.x * 256 + threadIdx.x;   // over B*S = 16384
    int b = idx >> 10, s = idx & 1023;
    int j = fpsidx[idx];
    const float* row = comb + ((size_t)b*NN + j) * 24;
    float* cr = cent + (size_t)idx * 24;
#pragma unroll
    for (int q = 0; q < 6; ++q) ((float4*)cr)[q] = ((const float4*)row)[q];
#pragma unroll
    for (int c = 0; c < 3; ++c) out0[((size_t)b*3 + c)*SS + s] = row[c];
    float* o2 = out2 + (size_t)idx * 20;
#pragma unroll
    for (int d = 0; d < 20; ++d) o2[d] = row[3 + d];
}

// ---------------------------------------------------------------------------
// 4) KNN v2: fp64 distance computation (validated R2/R4 numerics) downcast to
//    fp32 orderable u32 keys -> u[64] (no fp64 array, no spill). Exact top-32
//    SET via 32-step binary search for the 32nd value + ballot compaction
//    with ascending-index tie-break (order within the 32 is free downstream:
//    BN stats and max-over-K are permutation invariant).
// ---------------------------------------------------------------------------
__global__ __launch_bounds__(256) void k_knn(const float* __restrict__ comb,
                                             const float* __restrict__ cent,
                                             int* __restrict__ knn)
{
    int w = threadIdx.x >> 6, lane = threadIdx.x & 63;
    int r = blockIdx.x * 4 + w;     // row over B*S
    int b = r >> 10;
    const float* crow = cent + (size_t)r * 24;
    const float* P0 = comb + (size_t)b * NN * 24;
    double cc[24];
#pragma unroll
    for (int q = 0; q < 24; ++q) cc[q] = (double)crow[q];
    unsigned u[64];
#pragma unroll
    for (int k = 0; k < 64; ++k){
        int j = k*64 + lane;
        const float4* pr = (const float4*)(P0 + (size_t)j * 24);
        double acc = 0.0;
#pragma unroll
        for (int q = 0; q < 6; ++q){
            float4 v = pr[q];
            double d0 = (double)v.x - cc[4*q];
            double d1 = (double)v.y - cc[4*q+1];
            double d2 = (double)v.z - cc[4*q+2];
            double d3 = (double)v.w - cc[4*q+3];
            acc += d0*d0; acc += d1*d1; acc += d2*d2; acc += d3*d3;
        }
        u[k] = __float_as_uint((float)acc);   // >=0 -> bits are monotone
    }
    // binary search for T = value of the 32nd smallest key
    unsigned lo = 0u, hi = 0xFFFFFFFFu;
    for (int it = 0; it < 32; ++it){
        unsigned mid = lo + ((hi - lo) >> 1);
        int cnt = 0;
#pragma unroll
        for (int k = 0; k < 64; ++k) cnt += (u[k] <= mid) ? 1 : 0;
#pragma unroll
        for (int off = 32; off > 0; off >>= 1) cnt += __shfl_xor(cnt, off);
        if (cnt >= KK) hi = mid; else lo = mid + 1;
    }
    unsigned T = lo;
    int* orow = knn + (size_t)r * KK;
    unsigned long long lmask = (1ull << lane) - 1ull;
    int pos = 0;
#pragma unroll
    for (int k = 0; k < 64; ++k){
        bool lt = (u[k] < T);
        unsigned long long mk = __ballot(lt);
        if (lt) orow[pos + __popcll(mk & lmask)] = k*64 + lane;
        pos += __popcll(mk);
    }
#pragma unroll
    for (int k = 0; k < 64; ++k){
        if (pos >= KK) break;
        bool eq = (u[k] == T);
        unsigned long long mk = __ballot(eq);
        int rk = __popcll(mk & lmask);
        if (eq && (pos + rk) < KK) orow[pos + rk] = k*64 + lane;
        pos += __popcll(mk);
    }
}

// ---------------------------------------------------------------------------
// 5) layer 1: gather+normalize -> 24ch, GEMM 24->64, +bias -> yb bf16 [64][M]
// ---------------------------------------------------------------------------
__global__ __launch_bounds__(256) void k_l1(const float* __restrict__ comb,
                                            const float* __restrict__ cent,
                                            const int* __restrict__ knn,
                                            const float* __restrict__ w0,
                                            const float* __restrict__ b0,
                                            unsigned short* __restrict__ yb)
{
    __shared__ float Wt[24][64];
    __shared__ float Xt[24][68];
    int t = threadIdx.x;
    int m_base = blockIdx.x * 64;
    for (int i = t; i < 1536; i += 256){
        int o = i / 24, c = i - o*24;
        Wt[c][o] = w0[i];
    }
    {
        int sm = t & 63, g = t >> 6;
        int m = m_base + sm;
        int b = m >> 15;
        int row = m >> 5;
        int j = knn[m];
        const float* P  = comb + ((size_t)b*NN + j) * 24;
        const float* Cc = cent + (size_t)row * 24;
        if (g == 0){
            float dx = P[0]-Cc[0], dy = P[1]-Cc[1], dz = P[2]-Cc[2];
            Xt[0][sm] = dx; Xt[1][sm] = dy; Xt[2][sm] = dz;
            float n2 = dx*dx; n2 = fmaf(dy, dy, n2); n2 = fmaf(dz, dz, n2);
            Xt[3][sm] = sqrtf(fmaxf(n2, 1e-12f));
            Xt[4][sm] = P[3] - Cc[3];
            Xt[5][sm] = P[4] - Cc[4];
        } else {
#pragma unroll
            for (int cq = 0; cq < 6; ++cq){
                int c = 6*g + cq;
                Xt[c][sm] = P[c-1] - Cc[c-1];
            }
        }
    }
    __syncthreads();
    int i = t >> 4, jj = t & 15;
    float acc[4][4] = {};
#pragma unroll
    for (int c = 0; c < 24; ++c){
        float4 wv = *(const float4*)&Wt[c][i*4];
        float4 xv = *(const float4*)&Xt[c][jj*4];
        float wr[4] = {wv.x, wv.y, wv.z, wv.w};
        float xr[4] = {xv.x, xv.y, xv.z, xv.w};
#pragma unroll
        for (int a = 0; a < 4; ++a)
#pragma unroll
            for (int q = 0; q < 4; ++q) acc[a][q] = fmaf(wr[a], xr[q], acc[a][q]);
    }
#pragma unroll
    for (int oi = 0; oi < 4; ++oi){
        int o = i*4 + oi;
        float bb = b0[o];
        ushort4 rv;
        rv.x = f2bf(acc[oi][0]+bb); rv.y = f2bf(acc[oi][1]+bb);
        rv.z = f2bf(acc[oi][2]+bb); rv.w = f2bf(acc[oi][3]+bb);
        *(ushort4*)&yb[(size_t)o*MM + m_base + jj*4] = rv;
    }
}

// ---------------------------------------------------------------------------
// 6) per-channel sum/sumsq (fp64) over bf16 [64][M]
// ---------------------------------------------------------------------------
__global__ __launch_bounds__(256) void k_stats(const unsigned short* __restrict__ y,
                                               double* __restrict__ stats)
{
    const int chunks = 8;
    int c = blockIdx.x / chunks, ch = blockIdx.x % chunks;
    size_t base = (size_t)c * MM + (size_t)ch * (MM / chunks);
    double s1 = 0.0, s2 = 0.0;
    const unsigned short* p = y + base;
    for (int i = threadIdx.x; i < MM/chunks; i += 256){
        float v = bf2f(p[i]);
        s1 += v; s2 += (double)v * v;
    }
#pragma unroll
    for (int off = 32; off > 0; off >>= 1){
        s1 += __shfl_xor(s1, off);
        s2 += __shfl_xor(s2, off);
    }
    __shared__ double ps1[4], ps2[4];
    int w = threadIdx.x >> 6, lane = threadIdx.x & 63;
    if (lane == 0){ ps1[w] = s1; ps2[w] = s2; }
    __syncthreads();
    if (threadIdx.x == 0){
        atomicAdd(&stats[c*2 + 0], ps1[0]+ps1[1]+ps1[2]+ps1[3]);
        atomicAdd(&stats[c*2 + 1], ps2[0]+ps2[1]+ps2[2]+ps2[3]);
    }
}

__global__ void k_affine(const double* __restrict__ stats, float* __restrict__ params, int C)
{
    int c = threadIdx.x;
    if (c < C){
        double mu = stats[c*2] / (double)MM;
        double var = stats[c*2 + 1] / (double)MM - mu*mu;
        params[c*2 + 0] = (float)mu;
        params[c*2 + 1] = (float)(1.0 / sqrt(var + 1e-5));
    }
}

// ---------------------------------------------------------------------------
// 7) layer 2 IN-PLACE: bn1+relu(yb) -> GEMM 64->64 -> yb (same tile, bf16)
// ---------------------------------------------------------------------------
__global__ __launch_bounds__(256) void k_l2(unsigned short* __restrict__ yb,
                                            const float* __restrict__ prm,
                                            const float* __restrict__ gg,
                                            const float* __restrict__ bt,
                                            const float* __restrict__ w,
                                            const float* __restrict__ bias)
{
    __shared__ float Wt[64][64];
    __shared__ float Xt[64][68];
    int t = threadIdx.x;
    int m_base = blockIdx.x * 64;
    for (int i = t; i < 4096; i += 256){
        int o = i >> 6, c = i & 63;
        Wt[c][o] = w[i];
    }
#pragma unroll
    for (int rp = 0; rp < 16; ++rp){
        int idx = rp*256 + t;
        int c = idx >> 6, mm2 = idx & 63;
        float v = bf2f(yb[(size_t)c*MM + m_base + mm2]);
        float t1 = (v - prm[c*2]) * prm[c*2 + 1];
        Xt[c][mm2] = fmaxf(fmaf(t1, gg[c], bt[c]), 0.f);
    }
    __syncthreads();
    int i = t >> 4, jj = t & 15;
    float acc[4][4] = {};
#pragma unroll
    for (int c = 0; c < 64; ++c){
        float4 wv = *(const float4*)&Wt[c][i*4];
        float4 xv = *(const float4*)&Xt[c][jj*4];
        float wr[4] = {wv.x, wv.y, wv.z, wv.w};
        float xr[4] = {xv.x, xv.y, xv.z, xv.w};
#pragma unroll
        for (int a = 0; a < 4; ++a)
#pragma unroll
            for (int q = 0; q < 4; ++q) acc[a][q] = fmaf(wr[a], xr[q], acc[a][q]);
    }
    // all reads of this tile happened before the barrier above -> in-place safe
#pragma unroll
    for (int oi = 0; oi < 4; ++oi){
        int o = i*4 + oi;
        float bb = bias[o];
        ushort4 rv;
        rv.x = f2bf(acc[oi][0]+bb); rv.y = f2bf(acc[oi][1]+bb);
        rv.z = f2bf(acc[oi][2]+bb); rv.w = f2bf(acc[oi][3]+bb);
        *(ushort4*)&yb[(size_t)o*MM + m_base + jj*4] = rv;
    }
}

// ---------------------------------------------------------------------------
// 8) layer 3 stats pass: bn2+relu(yb) -> GEMM 64->128 in regs -> stats3 only
// ---------------------------------------------------------------------------
__global__ __launch_bounds__(256) void k_l3s(const unsigned short* __restrict__ yb,
                                             const float* __restrict__ prm,
                                             const float* __restrict__ gg,
                                             const float* __restrict__ bt,
                                             const float* __restrict__ w,
                                             const float* __restrict__ bias,
                                             double* __restrict__ stats)
{
    __shared__ float Wt[64][128];
    __shared__ float Xt[64][68];
    int t = threadIdx.x;
    for (int i = t; i < 8192; i += 256){
        int o = i >> 6, c = i & 63;
        Wt[c][o] = w[i];
    }
    int i = t >> 4, jj = t & 15;
    double s1[8] = {}, s2[8] = {};
    for (int tt = 0; tt < 16; ++tt){
        int m_base = (blockIdx.x * 16 + tt) * 64;
        __syncthreads();
#pragma unroll
        for (int rp = 0; rp < 16; ++rp){
            int idx = rp*256 + t;
            int c = idx >> 6, mm2 = idx & 63;
            float v = bf2f(yb[(size_t)c*MM + m_base + mm2]);
            float t1 = (v - prm[c*2]) * prm[c*2 + 1];
            Xt[c][mm2] = fmaxf(fmaf(t1, gg[c], bt[c]), 0.f);
        }
        __syncthreads();
        float acc[8][4] = {};
#pragma unroll
        for (int c = 0; c < 64; ++c){
            float4 w0v = *(const float4*)&Wt[c][i*8];
            float4 w1v = *(const float4*)&Wt[c][i*8 + 4];
            float4 xv  = *(const float4*)&Xt[c][jj*4];
            float wr[8] = {w0v.x, w0v.y, w0v.z, w0v.w, w1v.x, w1v.y, w1v.z, w1v.w};
            float xr[4] = {xv.x, xv.y, xv.z, xv.w};
#pragma unroll
            for (int a = 0; a < 8; ++a)
#pragma unroll
                for (int q = 0; q < 4; ++q) acc[a][q] = fmaf(wr[a], xr[q], acc[a][q]);
        }
#pragma unroll
        for (int oi = 0; oi < 8; ++oi){
            float bb = bias[i*8 + oi];
#pragma unroll
            for (int q = 0; q < 4; ++q){
                float v = acc[oi][q] + bb;
                s1[oi] += v;
                s2[oi] += (double)v * v;
            }
        }
    }
#pragma unroll
    for (int oi = 0; oi < 8; ++oi){
#pragma unroll
        for (int off = 1; off < 16; off <<= 1){
            s1[oi] += __shfl_xor(s1[oi], off);
            s2[oi] += __shfl_xor(s2[oi], off);
        }
    }
    if (jj == 0){
#pragma unroll
        for (int oi = 0; oi < 8; ++oi){
            int o = i*8 + oi;
            atomicAdd(&stats[o*2 + 0], s1[oi]);
            atomicAdd(&stats[o*2 + 1], s2[oi]);
        }
    }
}

// ---------------------------------------------------------------------------
// 9) final: recompute layer3 GEMM, bn3+relu, max over K -> out1 [B][128][S]
// ---------------------------------------------------------------------------
__global__ __launch_bounds__(256) void k_final(const unsigned short* __restrict__ yb,
                                               const float* __restrict__ prm2,
                                               const float* __restrict__ g1c,
                                               const float* __restrict__ bt1c,
                                               const float* __restrict__ w,
                                               const float* __restrict__ bias,
                                               const float* __restrict__ prm3,
                                               const float* __restrict__ g2c,
                                               const float* __restrict__ bt2c,
                                               float* __restrict__ out1)
{
    __shared__ float Wt[64][128];
    __shared__ float Xt[64][68];
    int t = threadIdx.x;
    int m_base = blockIdx.x * 64;
    for (int i = t; i < 8192; i += 256){
        int o = i >> 6, c = i & 63;
        Wt[c][o] = w[i];
    }
#pragma unroll
    for (int rp = 0; rp < 16; ++rp){
        int idx = rp*256 + t;
        int c = idx >> 6, mm2 = idx & 63;
        float v = bf2f(yb[(size_t)c*MM + m_base + mm2]);
        float t1 = (v - prm2[c*2]) * prm2[c*2 + 1];
        Xt[c][mm2] = fmaxf(fmaf(t1, g1c[c], bt1c[c]), 0.f);
    }
    __syncthreads();
    int i = t >> 4, jj = t & 15;
    float acc[8][4] = {};
#pragma unroll
    for (int c = 0; c < 64; ++c){
        float4 w0v = *(const float4*)&Wt[c][i*8];
        float4 w1v = *(const float4*)&Wt[c][i*8 + 4];
        float4 xv  = *(const float4*)&Xt[c][jj*4];
        float wr[8] = {w0v.x, w0v.y, w0v.z, w0v.w, w1v.x, w1v.y, w1v.z, w1v.w};
        float xr[4] = {xv.x, xv.y, xv.z, xv.w};
#pragma unroll
        for (int a = 0; a < 8; ++a)
#pragma unroll
            for (int q = 0; q < 4; ++q) acc[a][q] = fmaf(wr[a], xr[q], acc[a][q]);
    }
    float mx[8];
#pragma unroll
    for (int oi = 0; oi < 8; ++oi){
        int o = i*8 + oi;
        float bb = bias[o];
        float mu = prm3[o*2], inv = prm3[o*2 + 1], gv = g2c[o], bv = bt2c[o];
        float m = 0.f;   // relu'd values >= 0
#pragma unroll
        for (int q = 0; q < 4; ++q){
            float v = acc[oi][q] + bb;
            float r = fmaxf(fmaf((v - mu) * inv, gv, bv), 0.f);
            m = fmaxf(m, r);
        }
        mx[oi] = m;
    }
#pragma unroll
    for (int oi = 0; oi < 8; ++oi){
#pragma unroll
        for (int off = 1; off < 8; off <<= 1)
            mx[oi] = fmaxf(mx[oi], __shfl_xor(mx[oi], off));
    }
    if ((jj & 7) == 0){
        int rg = (m_base >> 5) + (jj >> 3);   // global row b*S+s
        int b = rg >> 10, s = rg & 1023;
#pragma unroll
        for (int oi = 0; oi < 8; ++oi)
            out1[(size_t)b*131072 + (size_t)(i*8 + oi)*1024 + s] = mx[oi];
    }
}

// ---------------------------------------------------------------------------
extern "C" void kernel_launch(void* const* d_in, const int* in_sizes, int n_in,
                              void* d_out, int out_size, void* d_ws, size_t ws_size,
                              hipStream_t stream)
{
    const float* xyz  = (const float*)d_in[0];
    const float* feat = (const float*)d_in[1];
    const float* w0 = (const float*)d_in[2];  const float* b0  = (const float*)d_in[3];
    const float* g0 = (const float*)d_in[4];  const float* bt0 = (const float*)d_in[5];
    const float* w1 = (const float*)d_in[6];  const float* b1  = (const float*)d_in[7];
    const float* g1 = (const float*)d_in[8];  const float* bt1 = (const float*)d_in[9];
    const float* w2 = (const float*)d_in[10]; const float* b2  = (const float*)d_in[11];
    const float* g2 = (const float*)d_in[12]; const float* bt2 = (const float*)d_in[13];

    float* out0 = (float*)d_out;
    float* out1 = (float*)d_out + 49152;
    float* out2 = (float*)d_out + 49152 + 2097152;

    if (ws_size < WS_NEED){
        k_fail<<<(out_size + 255)/256, 256, 0, stream>>>((float*)d_out, out_size);
        return;
    }

    char* ws = (char*)d_ws;
    double* stats = (double*)(ws + WS_STATS);
    float* params = (float*)(ws + WS_PARAMS);
    int*   fpsidx = (int*)(ws + WS_FPSIDX);
    float* cent   = (float*)(ws + WS_CENT);
    int*   knn    = (int*)(ws + WS_KNN);
    float* comb   = (float*)(ws + WS_COMB);
    unsigned short* yb = (unsigned short*)(ws + WS_YB);

    k_zstats<<<1,    256, 0, stream>>>(stats);
    k_build <<<256,  256, 0, stream>>>(xyz, feat, comb);
    k_fps   <<<16,   256, 0, stream>>>(comb, fpsidx);
    k_gather<<<64,   256, 0, stream>>>(comb, fpsidx, cent, out0, out2);
    k_knn   <<<4096, 256, 0, stream>>>(comb, cent, knn);
    k_l1    <<<8192, 256, 0, stream>>>(comb, cent, knn, w0, b0, yb);
    k_stats <<<512,  256, 0, stream>>>(yb, stats);
    k_affine<<<1,    128, 0, stream>>>(stats, params, 64);
    k_l2    <<<8192, 256, 0, stream>>>(yb, params, g0, bt0, w1, b1);
    k_stats <<<512,  256, 0, stream>>>(yb, stats + 256);
    k_affine<<<1,    128, 0, stream>>>(stats + 256, params + 256, 64);
    k_l3s   <<<512,  256, 0, stream>>>(yb, params + 256, g1, bt1, w2, b2, stats + 512);
    k_affine<<<1,    128, 0, stream>>>(stats + 512, params + 512, 128);
    k_final <<<8192, 256, 0, stream>>>(yb, params + 256, g1, bt1, w2, b2,
                                       params + 512, g2, bt2, out1);
}

// Round 7
// 3113.130 us; speedup vs baseline: 1.2261x; 1.2261x over previous
//
#include <hip/hip_runtime.h>

#define BB 16
#define NN 4096
#define DFEAT 20
#define SS 1024
#define KK 32
#define MM (BB*SS*KK)   // 524288

// ---- workspace layout (bytes), total ~73.6 MB ----
#define WS_STATS   0ull          // 8192   (1024 doubles: 3 layers x up to 256ch x {s1,s2})
#define WS_PARAMS  8192ull       // 4096   (floats: layer L at +L*256 floats: {mu,inv} per ch)
#define WS_FPSIDX  12288ull      // 65536
#define WS_CENT    81920ull      // 1572864  ([B*S][24] gathered combined rows)
#define WS_KNN     1654784ull    // 2097152  ([B*S][32] int)
#define WS_COMB    3751936ull    // 6291456  ([B*N][24] fp32, ch23 = 0 pad)
#define WS_YB      10043392ull   // 67108864 (bf16 [64][M]; y1 then overwritten in-place by y2)
#define WS_NEED    77152256ull

typedef float v2f __attribute__((ext_vector_type(2)));

static __device__ __forceinline__ unsigned short f2bf(float f){
    unsigned u = __float_as_uint(f);
    unsigned r = (u + 0x7FFFu + ((u >> 16) & 1u)) >> 16;
    return (unsigned short)r;
}
static __device__ __forceinline__ float bf2f(unsigned short v){
    return __uint_as_float((unsigned)v << 16);
}
// pin a v2f pair into an (even-aligned) ARCH VGPR pair. Empty asm, zero
// instructions. Applied INSIDE the FPS loop so the allocator cannot give the
// value an AGPR home between iterations (R6 lesson: ISA addresses only 256
// arch VGPRs/wave; AGPR homes cost one v_accvgpr_read per use per iter).
static __device__ __forceinline__ void pinv2(v2f& x){
    asm volatile("" : "+v"(x));
}

static __device__ __forceinline__ unsigned long long max64(unsigned long long a, unsigned long long b){
    return a > b ? a : b;
}
// 32-bit DPP-shifted copy; bound_ctrl=1 -> invalid source lanes read 0,
// identity for unsigned max (our operands are > 0 where it matters).
template<int CTRL>
static __device__ __forceinline__ unsigned dpp32_or0(unsigned x){
    return (unsigned)__builtin_amdgcn_update_dpp(0, (int)x, CTRL, 0xf, 0xf, true);
}
static __device__ __forceinline__ unsigned umax32(unsigned a, unsigned b){
    return a > b ? a : b;
}
// wave-wide max chain; full-wave result valid in lane 63
static __device__ __forceinline__ unsigned wave_max_u32(unsigned x){
    x = umax32(x, dpp32_or0<0x111>(x));   // row_shr:1
    x = umax32(x, dpp32_or0<0x112>(x));   // row_shr:2
    x = umax32(x, dpp32_or0<0x114>(x));   // row_shr:4
    x = umax32(x, dpp32_or0<0x118>(x));   // row_shr:8
    x = umax32(x, dpp32_or0<0x142>(x));   // row_bcast:15
    x = umax32(x, dpp32_or0<0x143>(x));   // row_bcast:31
    return x;
}

// ---------------------------------------------------------------------------
// 0) zero the stats area (1024 doubles)
// ---------------------------------------------------------------------------
__global__ void k_zstats(double* __restrict__ stats){
    int t = threadIdx.x;
#pragma unroll
    for (int i = 0; i < 4; ++i) stats[i*256 + t] = 0.0;
}

// fallback when ws is too small: zero d_out so the harness fails cleanly
__global__ void k_fail(float* __restrict__ out, int n){
    int i = blockIdx.x * 256 + threadIdx.x;
    if (i < n) out[i] = 0.f;
}

// ---------------------------------------------------------------------------
// 1) build combined [B][N][24] (ch23 = 0 pad)
// ---------------------------------------------------------------------------
__global__ __launch_bounds__(256) void k_build(const float* __restrict__ xyz,
                                               const float* __restrict__ feat,
                                               float* __restrict__ comb)
{
    int idx = blockIdx.x * 256 + threadIdx.x;   // over B*N = 65536
    int b = idx >> 12, j = idx & 4095;
    float c[24];
    c[0] = xyz[((size_t)b*3 + 0)*NN + j];
    c[1] = xyz[((size_t)b*3 + 1)*NN + j];
    c[2] = xyz[((size_t)b*3 + 2)*NN + j];
    const float* f = feat + ((size_t)b*NN + j)*DFEAT;
#pragma unroll
    for (int d = 0; d < 20; ++d) c[3+d] = f[d];
    c[23] = 0.f;
    float* out = comb + (size_t)idx * 24;
#pragma unroll
    for (int q = 0; q < 6; ++q)
        ((float4*)out)[q] = make_float4(c[4*q], c[4*q+1], c[4*q+2], c[4*q+3]);
}

// ---------------------------------------------------------------------------
// 2) FPS v10: the R6 accounting showed the dominant cost in every version so
//    far was the AGPR register-file tax: the allocator homes the point set in
//    AGPRs (ISA limit: 256 addressable arch VGPRs/wave) and pays one
//    v_accvgpr_read per point-float per iteration. The 512-thread / 8-point
//    config is the ONLY one whose live set (~184 pt floats + ~45 overhead
//    = ~230) fits entirely in arch VGPRs at 2 waves/SIMD. v10 = that config
//    with the pin RE-ASSERTED EVERY ITERATION (zero-instruction empty asm),
//    making an AGPR home illegal-or-costly so the allocator keeps points in
//    arch VGPRs.
//    All logic pieces individually validated: packed v2f distance chains in
//    v4's per-point order (R3/R5/R6), LDS fpsidx buffer + single flush
//    (v8/v9), two-chain 32-bit DPP stage-1 (v8/v9), lane-63 wkey write +
//    broadcast register-tree stage-2 (R2/v9), winner-register stash (R1+).
//    Selection bit-identical to all passing versions.
// ---------------------------------------------------------------------------
__global__ __launch_bounds__(512, 2) void k_fps(const float* __restrict__ comb,
                                                int* __restrict__ fpsidx)
{
    int b = blockIdx.x, t = threadIdx.x;
    const float* C = comb + (size_t)b * NN * 24;
    // pt2[k][q] = channel q of points {2k, 2k+1}; point p lives at global
    // index t + 512*p, i.e. element (p&1) of pair (p>>1)
    v2f pt2[4][24];
    v2f dist2[4];
#pragma unroll
    for (int p = 0; p < 8; ++p){
        const float4* r = (const float4*)(C + (size_t)(t + 512*p) * 24);
#pragma unroll
        for (int q = 0; q < 6; ++q){
            float4 v = r[q];
            pt2[p>>1][4*q+0][p&1] = v.x;
            pt2[p>>1][4*q+1][p&1] = v.y;
            pt2[p>>1][4*q+2][p&1] = v.z;
            pt2[p>>1][4*q+3][p&1] = v.w;
        }
    }
#pragma unroll
    for (int k = 0; k < 4; ++k)
        dist2[k] = (v2f){1e10f, 1e10f};

    __shared__ __align__(16) unsigned long long wkey[2][8];
    __shared__ __align__(16) float wpt[2][8][24];
    __shared__ int fps_lds[SS];
    int lane = t & 63, w = t >> 6;           // 8 waves
    unsigned nt = 0xFFFFFFFFu - (unsigned)t;
    int far = 0;

    float cc[24];
    {
        const float4* crow = (const float4*)C;   // initial centroid: row 0
#pragma unroll
        for (int q = 0; q < 6; ++q){
            float4 cv = crow[q];
            cc[4*q] = cv.x; cc[4*q+1] = cv.y; cc[4*q+2] = cv.z; cc[4*q+3] = cv.w;
        }
    }

    for (int s = 0; s < SS; ++s){
        // re-pin the point set THIS iteration: zero instructions, but forces
        // every pair to have an arch-VGPR home here -> no AGPR round-trips
#pragma unroll
        for (int k = 0; k < 4; ++k)
#pragma unroll
            for (int q = 0; q < 23; ++q) pinv2(pt2[k][q]);   // ch23 unused -> dies

        if (t == 0) fps_lds[s] = far;          // LDS only; flushed post-loop
        // ---- distance update: per-point chain EXACTLY v4's order, executed
        //      as 4 packed float2 chains (each half = one point's scalar
        //      sequence; VOP3P fp32 is IEEE-identical to scalar fp32).
        v2f acc2[4];
#pragma unroll
        for (int k = 0; k < 4; ++k){
            v2f d0 = pt2[k][0] - cc[0];
            acc2[k] = d0 * d0;
        }
#pragma unroll
        for (int q = 1; q < 23; ++q){
            float cq = cc[q];
#pragma unroll
            for (int k = 0; k < 4; ++k){
                v2f dd = pt2[k][q] - cq;
                acc2[k] = __builtin_elementwise_fma(dd, dd, acc2[k]);
            }
        }
        // packed min-update + packed max tree (bit-identical per element;
        // float max == bits max for non-negative values, any tree shape)
#pragma unroll
        for (int k = 0; k < 4; ++k)
            dist2[k] = __builtin_elementwise_min(dist2[k], acc2[k]);
        v2f m01 = __builtin_elementwise_max(dist2[0], dist2[1]);
        v2f m23 = __builtin_elementwise_max(dist2[2], dist2[3]);
        v2f mt  = __builtin_elementwise_max(m01, m23);
        float mf = fmaxf(mt[0], mt[1]);
        unsigned maxbits = __float_as_uint(mf);    // >=0 -> bits monotone
        // smallest p whose dist-bits equal the max -> min global idx among ties
        int pstar = 0;
#pragma unroll
        for (int p = 7; p >= 0; --p)
            if (__float_as_uint(dist2[p>>1][p&1]) == maxbits) pstar = p;

        // ---- stage-1a: wave max of dist bits (32-bit DPP chain) ----
        unsigned M = __builtin_amdgcn_readlane((int)wave_max_u32(maxbits), 63);
        // ---- stage-1b: among tied lanes, wave max of complemented index
        //      (== min index; 0-fill / non-tied lanes can never win) ----
        unsigned cidx = (maxbits == M) ? (nt - ((unsigned)pstar << 9)) : 0u;
        unsigned widxc = __builtin_amdgcn_readlane((int)wave_max_u32(cidx), 63);
        unsigned widx  = 0xFFFFFFFFu - widxc;      // wave winner global index

        int par = s & 1;
        if (lane == 63)
            wkey[par][w] = ((unsigned long long)M << 32) | (unsigned long long)widxc;
        // wave-winner thread stashes its point row (registers -> LDS, bit-exact)
        if (t == (int)(widx & 511u)){
            int pw = (int)(widx >> 9);
            float* dst = wpt[par][w];
            switch (pw){
#define PE(P,q) pt2[(P)>>1][q][(P)&1]
#define STASH(P) case P: \
                ((float4*)dst)[0] = make_float4(PE(P,0),PE(P,1),PE(P,2),PE(P,3)); \
                ((float4*)dst)[1] = make_float4(PE(P,4),PE(P,5),PE(P,6),PE(P,7)); \
                ((float4*)dst)[2] = make_float4(PE(P,8),PE(P,9),PE(P,10),PE(P,11)); \
                ((float4*)dst)[3] = make_float4(PE(P,12),PE(P,13),PE(P,14),PE(P,15)); \
                ((float4*)dst)[4] = make_float4(PE(P,16),PE(P,17),PE(P,18),PE(P,19)); \
                ((float4*)dst)[5] = make_float4(PE(P,20),PE(P,21),PE(P,22),0.f); \
                break;   // cc[23] never read; keep pt2[][23] dead
            STASH(0) STASH(1) STASH(2) STASH(3)
            STASH(4) STASH(5) STASH(6) STASH(7)
#undef STASH
#undef PE
            }
        }
        __syncthreads();
        // ---- stage-2: broadcast-read the 8 wave keys, register tree max ----
        const ulonglong2* kp = (const ulonglong2*)wkey[par];
        ulonglong2 q0 = kp[0], q1 = kp[1], q2 = kp[2], q3 = kp[3];
        unsigned long long k2 = max64(max64(max64(q0.x, q0.y), max64(q1.x, q1.y)),
                                      max64(max64(q2.x, q2.y), max64(q3.x, q3.y)));
        far = (int)(0xFFFFFFFFu - (unsigned)(k2 & 0xFFFFFFFFull));
        // next centroid from the winner's stashed registers (LDS broadcast)
        int wg = (far & 511) >> 6;
        const float4* crow = (const float4*)wpt[par][wg];
#pragma unroll
        for (int q = 0; q < 6; ++q){
            float4 cv = crow[q];
            cc[4*q] = cv.x; cc[4*q+1] = cv.y; cc[4*q+2] = cv.z; cc[4*q+3] = cv.w;
        }
    }
    // flush fpsidx (coalesced, once)
    __syncthreads();
    fpsidx[b*SS + t]       = fps_lds[t];
    fpsidx[b*SS + 512 + t] = fps_lds[512 + t];
}

// ---------------------------------------------------------------------------
// 3) gather centroids + outputs 0 and 2 (exact gathers)
// ---------------------------------------------------------------------------
__global__ __launch_bounds__(256) void k_gather(const float* __restrict__ comb,
                                                const int* __restrict__ fpsidx,
                                                float* __restrict__ cent,
                                                float* __restrict__ out0,
                                                float* __restrict__ out2)
{
    int idx = blockIdx.x * 256 + threadIdx.x;   // over B*S = 16384
    int b = idx >> 10, s = idx & 1023;
    int j = fpsidx[idx];
    const float* row = comb + ((size_t)b*NN + j) * 24;
    float* cr = cent + (size_t)idx * 24;
#pragma unroll
    for (int q = 0; q < 6; ++q) ((float4*)cr)[q] = ((const float4*)row)[q];
#pragma unroll
    for (int c = 0; c < 3; ++c) out0[((size_t)b*3 + c)*SS + s] = row[c];
    float* o2 = out2 + (size_t)idx * 20;
#pragma unroll
    for (int d = 0; d < 20; ++d) o2[d] = row[3 + d];
}

// ---------------------------------------------------------------------------
// 4) KNN v2: fp64 distance computation (validated R2/R4 numerics) downcast to
//    fp32 orderable u32 keys -> u[64] (no fp64 array, no spill). Exact top-32
//    SET via 32-step binary search for the 32nd value + ballot compaction
//    with ascending-index tie-break (order within the 32 is free downstream:
//    BN stats and max-over-K are permutation invariant).
// ---------------------------------------------------------------------------
__global__ __launch_bounds__(256) void k_knn(const float* __restrict__ comb,
                                             const float* __restrict__ cent,
                                             int* __restrict__ knn)
{
    int w = threadIdx.x >> 6, lane = threadIdx.x & 63;
    int r = blockIdx.x * 4 + w;     // row over B*S
    int b = r >> 10;
    const float* crow = cent + (size_t)r * 24;
    const float* P0 = comb + (size_t)b * NN * 24;
    double cc[24];
#pragma unroll
    for (int q = 0; q < 24; ++q) cc[q] = (double)crow[q];
    unsigned u[64];
#pragma unroll
    for (int k = 0; k < 64; ++k){
        int j = k*64 + lane;
        const float4* pr = (const float4*)(P0 + (size_t)j * 24);
        double acc = 0.0;
#pragma unroll
        for (int q = 0; q < 6; ++q){
            float4 v = pr[q];
            double d0 = (double)v.x - cc[4*q];
            double d1 = (double)v.y - cc[4*q+1];
            double d2 = (double)v.z - cc[4*q+2];
            double d3 = (double)v.w - cc[4*q+3];
            acc += d0*d0; acc += d1*d1; acc += d2*d2; acc += d3*d3;
        }
        u[k] = __float_as_uint((float)acc);   // >=0 -> bits are monotone
    }
    // binary search for T = value of the 32nd smallest key
    unsigned lo = 0u, hi = 0xFFFFFFFFu;
    for (int it = 0; it < 32; ++it){
        unsigned mid = lo + ((hi - lo) >> 1);
        int cnt = 0;
#pragma unroll
        for (int k = 0; k < 64; ++k) cnt += (u[k] <= mid) ? 1 : 0;
#pragma unroll
        for (int off = 32; off > 0; off >>= 1) cnt += __shfl_xor(cnt, off);
        if (cnt >= KK) hi = mid; else lo = mid + 1;
    }
    unsigned T = lo;
    int* orow = knn + (size_t)r * KK;
    unsigned long long lmask = (1ull << lane) - 1ull;
    int pos = 0;
#pragma unroll
    for (int k = 0; k < 64; ++k){
        bool lt = (u[k] < T);
        unsigned long long mk = __ballot(lt);
        if (lt) orow[pos + __popcll(mk & lmask)] = k*64 + lane;
        pos += __popcll(mk);
    }
#pragma unroll
    for (int k = 0; k < 64; ++k){
        if (pos >= KK) break;
        bool eq = (u[k] == T);
        unsigned long long mk = __ballot(eq);
        int rk = __popcll(mk & lmask);
        if (eq && (pos + rk) < KK) orow[pos + rk] = k*64 + lane;
        pos += __popcll(mk);
    }
}

// ---------------------------------------------------------------------------
// 5) layer 1: gather+normalize -> 24ch, GEMM 24->64, +bias -> yb bf16 [64][M]
// ---------------------------------------------------------------------------
__global__ __launch_bounds__(256) void k_l1(const float* __restrict__ comb,
                                            const float* __restrict__ cent,
                                            const int* __restrict__ knn,
                                            const float* __restrict__ w0,
                                            const float* __restrict__ b0,
                                            unsigned short* __restrict__ yb)
{
    __shared__ float Wt[24][64];
    __shared__ float Xt[24][68];
    int t = threadIdx.x;
    int m_base = blockIdx.x * 64;
    for (int i = t; i < 1536; i += 256){
        int o = i / 24, c = i - o*24;
        Wt[c][o] = w0[i];
    }
    {
        int sm = t & 63, g = t >> 6;
        int m = m_base + sm;
        int b = m >> 15;
        int row = m >> 5;
        int j = knn[m];
        const float* P  = comb + ((size_t)b*NN + j) * 24;
        const float* Cc = cent + (size_t)row * 24;
        if (g == 0){
            float dx = P[0]-Cc[0], dy = P[1]-Cc[1], dz = P[2]-Cc[2];
            Xt[0][sm] = dx; Xt[1][sm] = dy; Xt[2][sm] = dz;
            float n2 = dx*dx; n2 = fmaf(dy, dy, n2); n2 = fmaf(dz, dz, n2);
            Xt[3][sm] = sqrtf(fmaxf(n2, 1e-12f));
            Xt[4][sm] = P[3] - Cc[3];
            Xt[5][sm] = P[4] - Cc[4];
        } else {
#pragma unroll
            for (int cq = 0; cq < 6; ++cq){
                int c = 6*g + cq;
                Xt[c][sm] = P[c-1] - Cc[c-1];
            }
        }
    }
    __syncthreads();
    int i = t >> 4, jj = t & 15;
    float acc[4][4] = {};
#pragma unroll
    for (int c = 0; c < 24; ++c){
        float4 wv = *(const float4*)&Wt[c][i*4];
        float4 xv = *(const float4*)&Xt[c][jj*4];
        float wr[4] = {wv.x, wv.y, wv.z, wv.w};
        float xr[4] = {xv.x, xv.y, xv.z, xv.w};
#pragma unroll
        for (int a = 0; a < 4; ++a)
#pragma unroll
            for (int q = 0; q < 4; ++q) acc[a][q] = fmaf(wr[a], xr[q], acc[a][q]);
    }
#pragma unroll
    for (int oi = 0; oi < 4; ++oi){
        int o = i*4 + oi;
        float bb = b0[o];
        ushort4 rv;
        rv.x = f2bf(acc[oi][0]+bb); rv.y = f2bf(acc[oi][1]+bb);
        rv.z = f2bf(acc[oi][2]+bb); rv.w = f2bf(acc[oi][3]+bb);
        *(ushort4*)&yb[(size_t)o*MM + m_base + jj*4] = rv;
    }
}

// ---------------------------------------------------------------------------
// 6) per-channel sum/sumsq (fp64) over bf16 [64][M]
// ---------------------------------------------------------------------------
__global__ __launch_bounds__(256) void k_stats(const unsigned short* __restrict__ y,
                                               double* __restrict__ stats)
{
    const int chunks = 8;
    int c = blockIdx.x / chunks, ch = blockIdx.x % chunks;
    size_t base = (size_t)c * MM + (size_t)ch * (MM / chunks);
    double s1 = 0.0, s2 = 0.0;
    const unsigned short* p = y + base;
    for (int i = threadIdx.x; i < MM/chunks; i += 256){
        float v = bf2f(p[i]);
        s1 += v; s2 += (double)v * v;
    }
#pragma unroll
    for (int off = 32; off > 0; off >>= 1){
        s1 += __shfl_xor(s1, off);
        s2 += __shfl_xor(s2, off);
    }
    __shared__ double ps1[4], ps2[4];
    int w = threadIdx.x >> 6, lane = threadIdx.x & 63;
    if (lane == 0){ ps1[w] = s1; ps2[w] = s2; }
    __syncthreads();
    if (threadIdx.x == 0){
        atomicAdd(&stats[c*2 + 0], ps1[0]+ps1[1]+ps1[2]+ps1[3]);
        atomicAdd(&stats[c*2 + 1], ps2[0]+ps2[1]+ps2[2]+ps2[3]);
    }
}

__global__ void k_affine(const double* __restrict__ stats, float* __restrict__ params, int C)
{
    int c = threadIdx.x;
    if (c < C){
        double mu = stats[c*2] / (double)MM;
        double var = stats[c*2 + 1] / (double)MM - mu*mu;
        params[c*2 + 0] = (float)mu;
        params[c*2 + 1] = (float)(1.0 / sqrt(var + 1e-5));
    }
}

// ---------------------------------------------------------------------------
// 7) layer 2 IN-PLACE: bn1+relu(yb) -> GEMM 64->64 -> yb (same tile, bf16)
// ---------------------------------------------------------------------------
__global__ __launch_bounds__(256) void k_l2(unsigned short* __restrict__ yb,
                                            const float* __restrict__ prm,
                                            const float* __restrict__ gg,
                                            const float* __restrict__ bt,
                                            const float* __restrict__ w,
                                            const float* __restrict__ bias)
{
    __shared__ float Wt[64][64];
    __shared__ float Xt[64][68];
    int t = threadIdx.x;
    int m_base = blockIdx.x * 64;
    for (int i = t; i < 4096; i += 256){
        int o = i >> 6, c = i & 63;
        Wt[c][o] = w[i];
    }
#pragma unroll
    for (int rp = 0; rp < 16; ++rp){
        int idx = rp*256 + t;
        int c = idx >> 6, mm2 = idx & 63;
        float v = bf2f(yb[(size_t)c*MM + m_base + mm2]);
        float t1 = (v - prm[c*2]) * prm[c*2 + 1];
        Xt[c][mm2] = fmaxf(fmaf(t1, gg[c], bt[c]), 0.f);
    }
    __syncthreads();
    int i = t >> 4, jj = t & 15;
    float acc[4][4] = {};
#pragma unroll
    for (int c = 0; c < 64; ++c){
        float4 wv = *(const float4*)&Wt[c][i*4];
        float4 xv = *(const float4*)&Xt[c][jj*4];
        float wr[4] = {wv.x, wv.y, wv.z, wv.w};
        float xr[4] = {xv.x, xv.y, xv.z, xv.w};
#pragma unroll
        for (int a = 0; a < 4; ++a)
#pragma unroll
            for (int q = 0; q < 4; ++q) acc[a][q] = fmaf(wr[a], xr[q], acc[a][q]);
    }
    // all reads of this tile happened before the barrier above -> in-place safe
#pragma unroll
    for (int oi = 0; oi < 4; ++oi){
        int o = i*4 + oi;
        float bb = bias[o];
        ushort4 rv;
        rv.x = f2bf(acc[oi][0]+bb); rv.y = f2bf(acc[oi][1]+bb);
        rv.z = f2bf(acc[oi][2]+bb); rv.w = f2bf(acc[oi][3]+bb);
        *(ushort4*)&yb[(size_t)o*MM + m_base + jj*4] = rv;
    }
}

// ---------------------------------------------------------------------------
// 8) layer 3 stats pass: bn2+relu(yb) -> GEMM 64->128 in regs -> stats3 only
// ---------------------------------------------------------------------------
__global__ __launch_bounds__(256) void k_l3s(const unsigned short* __restrict__ yb,
                                             const float* __restrict__ prm,
                                             const float* __restrict__ gg,
                                             const float* __restrict__ bt,
                                             const float* __restrict__ w,
                                             const float* __restrict__ bias,
                                             double* __restrict__ stats)
{
    __shared__ float Wt[64][128];
    __shared__ float Xt[64][68];
    int t = threadIdx.x;
    for (int i = t; i < 8192; i += 256){
        int o = i >> 6, c = i & 63;
        Wt[c][o] = w[i];
    }
    int i = t >> 4, jj = t & 15;
    double s1[8] = {}, s2[8] = {};
    for (int tt = 0; tt < 16; ++tt){
        int m_base = (blockIdx.x * 16 + tt) * 64;
        __syncthreads();
#pragma unroll
        for (int rp = 0; rp < 16; ++rp){
            int idx = rp*256 + t;
            int c = idx >> 6, mm2 = idx & 63;
            float v = bf2f(yb[(size_t)c*MM + m_base + mm2]);
            float t1 = (v - prm[c*2]) * prm[c*2 + 1];
            Xt[c][mm2] = fmaxf(fmaf(t1, gg[c], bt[c]), 0.f);
        }
        __syncthreads();
        float acc[8][4] = {};
#pragma unroll
        for (int c = 0; c < 64; ++c){
            float4 w0v = *(const float4*)&Wt[c][i*8];
            float4 w1v = *(const float4*)&Wt[c][i*8 + 4];
            float4 xv  = *(const float4*)&Xt[c][jj*4];
            float wr[8] = {w0v.x, w0v.y, w0v.z, w0v.w, w1v.x, w1v.y, w1v.z, w1v.w};
            float xr[4] = {xv.x, xv.y, xv.z, xv.w};
#pragma unroll
            for (int a = 0; a < 8; ++a)
#pragma unroll
                for (int q = 0; q < 4; ++q) acc[a][q] = fmaf(wr[a], xr[q], acc[a][q]);
        }
#pragma unroll
        for (int oi = 0; oi < 8; ++oi){
            float bb = bias[i*8 + oi];
#pragma unroll
            for (int q = 0; q < 4; ++q){
                float v = acc[oi][q] + bb;
                s1[oi] += v;
                s2[oi] += (double)v * v;
            }
        }
    }
#pragma unroll
    for (int oi = 0; oi < 8; ++oi){
#pragma unroll
        for (int off = 1; off < 16; off <<= 1){
            s1[oi] += __shfl_xor(s1[oi], off);
            s2[oi] += __shfl_xor(s2[oi], off);
        }
    }
    if (jj == 0){
#pragma unroll
        for (int oi = 0; oi < 8; ++oi){
            int o = i*8 + oi;
            atomicAdd(&stats[o*2 + 0], s1[oi]);
            atomicAdd(&stats[o*2 + 1], s2[oi]);
        }
    }
}

// ---------------------------------------------------------------------------
// 9) final: recompute layer3 GEMM, bn3+relu, max over K -> out1 [B][128][S]
// ---------------------------------------------------------------------------
__global__ __launch_bounds__(256) void k_final(const unsigned short* __restrict__ yb,
                                               const float* __restrict__ prm2,
                                               const float* __restrict__ g1c,
                                               const float* __restrict__ bt1c,
                                               const float* __restrict__ w,
                                               const float* __restrict__ bias,
                                               const float* __restrict__ prm3,
                                               const float* __restrict__ g2c,
                                               const float* __restrict__ bt2c,
                                               float* __restrict__ out1)
{
    __shared__ float Wt[64][128];
    __shared__ float Xt[64][68];
    int t = threadIdx.x;
    int m_base = blockIdx.x * 64;
    for (int i = t; i < 8192; i += 256){
        int o = i >> 6, c = i & 63;
        Wt[c][o] = w[i];
    }
#pragma unroll
    for (int rp = 0; rp < 16; ++rp){
        int idx = rp*256 + t;
        int c = idx >> 6, mm2 = idx & 63;
        float v = bf2f(yb[(size_t)c*MM + m_base + mm2]);
        float t1 = (v - prm2[c*2]) * prm2[c*2 + 1];
        Xt[c][mm2] = fmaxf(fmaf(t1, g1c[c], bt1c[c]), 0.f);
    }
    __syncthreads();
    int i = t >> 4, jj = t & 15;
    float acc[8][4] = {};
#pragma unroll
    for (int c = 0; c < 64; ++c){
        float4 w0v = *(const float4*)&Wt[c][i*8];
        float4 w1v = *(const float4*)&Wt[c][i*8 + 4];
        float4 xv  = *(const float4*)&Xt[c][jj*4];
        float wr[8] = {w0v.x, w0v.y, w0v.z, w0v.w, w1v.x, w1v.y, w1v.z, w1v.w};
        float xr[4] = {xv.x, xv.y, xv.z, xv.w};
#pragma unroll
        for (int a = 0; a < 8; ++a)
#pragma unroll
            for (int q = 0; q < 4; ++q) acc[a][q] = fmaf(wr[a], xr[q], acc[a][q]);
    }
    float mx[8];
#pragma unroll
    for (int oi = 0; oi < 8; ++oi){
        int o = i*8 + oi;
        float bb = bias[o];
        float mu = prm3[o*2], inv = prm3[o*2 + 1], gv = g2c[o], bv = bt2c[o];
        float m = 0.f;   // relu'd values >= 0
#pragma unroll
        for (int q = 0; q < 4; ++q){
            float v = acc[oi][q] + bb;
            float r = fmaxf(fmaf((v - mu) * inv, gv, bv), 0.f);
            m = fmaxf(m, r);
        }
        mx[oi] = m;
    }
#pragma unroll
    for (int oi = 0; oi < 8; ++oi){
#pragma unroll
        for (int off = 1; off < 8; off <<= 1)
            mx[oi] = fmaxf(mx[oi], __shfl_xor(mx[oi], off));
    }
    if ((jj & 7) == 0){
        int rg = (m_base >> 5) + (jj >> 3);   // global row b*S+s
        int b = rg >> 10, s = rg & 1023;
#pragma unroll
        for (int oi = 0; oi < 8; ++oi)
            out1[(size_t)b*131072 + (size_t)(i*8 + oi)*1024 + s] = mx[oi];
    }
}

// ---------------------------------------------------------------------------
extern "C" void kernel_launch(void* const* d_in, const int* in_sizes, int n_in,
                              void* d_out, int out_size, void* d_ws, size_t ws_size,
                              hipStream_t stream)
{
    const float* xyz  = (const float*)d_in[0];
    const float* feat = (const float*)d_in[1];
    const float* w0 = (const float*)d_in[2];  const float* b0  = (const float*)d_in[3];
    const float* g0 = (const float*)d_in[4];  const float* bt0 = (const float*)d_in[5];
    const float* w1 = (const float*)d_in[6];  const float* b1  = (const float*)d_in[7];
    const float* g1 = (const float*)d_in[8];  const float* bt1 = (const float*)d_in[9];
    const float* w2 = (const float*)d_in[10]; const float* b2  = (const float*)d_in[11];
    const float* g2 = (const float*)d_in[12]; const float* bt2 = (const float*)d_in[13];

    float* out0 = (float*)d_out;
    float* out1 = (float*)d_out + 49152;
    float* out2 = (float*)d_out + 49152 + 2097152;

    if (ws_size < WS_NEED){
        k_fail<<<(out_size + 255)/256, 256, 0, stream>>>((float*)d_out, out_size);
        return;
    }

    char* ws = (char*)d_ws;
    double* stats = (double*)(ws + WS_STATS);
    float* params = (float*)(ws + WS_PARAMS);
    int*   fpsidx = (int*)(ws + WS_FPSIDX);
    float* cent   = (float*)(ws + WS_CENT);
    int*   knn    = (int*)(ws + WS_KNN);
    float* comb   = (float*)(ws + WS_COMB);
    unsigned short* yb = (unsigned short*)(ws + WS_YB);

    k_zstats<<<1,    256, 0, stream>>>(stats);
    k_build <<<256,  256, 0, stream>>>(xyz, feat, comb);
    k_fps   <<<16,   512, 0, stream>>>(comb, fpsidx);
    k_gather<<<64,   256, 0, stream>>>(comb, fpsidx, cent, out0, out2);
    k_knn   <<<4096, 256, 0, stream>>>(comb, cent, knn);
    k_l1    <<<8192, 256, 0, stream>>>(comb, cent, knn, w0, b0, yb);
    k_stats <<<512,  256, 0, stream>>>(yb, stats);
    k_affine<<<1,    128, 0, stream>>>(stats, params, 64);
    k_l2    <<<8192, 256, 0, stream>>>(yb, params, g0, bt0, w1, b1);
    k_stats <<<512,  256, 0, stream>>>(yb, stats + 256);
    k_affine<<<1,    128, 0, stream>>>(stats + 256, params + 256, 64);
    k_l3s   <<<512,  256, 0, stream>>>(yb, params + 256, g1, bt1, w2, b2, stats + 512);
    k_affine<<<1,    128, 0, stream>>>(stats + 512, params + 512, 128);
    k_final <<<8192, 256, 0, stream>>>(yb, params + 256, g1, bt1, w2, b2,
                                       params + 512, g2, bt2, out1);
}